// Round 2
// baseline (7737.727 us; speedup 1.0000x reference)
//
#include <hip/hip_runtime.h>
#include <cstddef>

#define B_    4
#define T_    16384
#define WD_   128
#define SD_   512
#define FOUT_ 14337
#define NL_   20

// Static device buffers: allocated at module load -> no dependence on ws_size,
// safe under graph capture. Every element read in a call is written earlier in
// the same call (embed fills x0; layer0 (first=1) fully overwrites skip).
__device__ float g_x0[(size_t)B_*T_*WD_];     // 32 MB
__device__ float g_x1[(size_t)B_*T_*WD_];     // 32 MB
__device__ float g_skip[(size_t)B_*FOUT_*SD_]; // 112 MB (reused in-place as h1)

__device__ __forceinline__ float sigm_(float x){ return 1.0f/(1.0f+__expf(-x)); }
__device__ __forceinline__ float tanh_(float x){ return 1.0f - 2.0f/(__expf(2.0f*x)+1.0f); }

// ---------------- embedding: x0[b][t][c] = embed[y[b][t]][c] ----------------
__global__ void embed_kernel(const int* __restrict__ y, const float* __restrict__ embed){
  int gid = blockIdx.x*256 + threadIdx.x;
  int bt  = gid >> 5;
  int c4  = gid & 31;
  if (bt < B_*T_){
    int idx = y[bt];
    float4 v = ((const float4*)embed)[(size_t)idx*32 + c4];
    ((float4*)g_x0)[(size_t)bt*32 + c4] = v;
  }
}

// ---------------- fused per-layer kernel ----------------
// x layout: [B][T_][128] (position-major, channel contiguous), stride fixed at T_.
// Computes: in_act = Wd0@x[t] + Wd1@x[t+d] + bd; acts = tanh*sigmoid;
//           xout[t] = Wr@acts + br + x[t+d];  skip[ts] += Ws@acts + bs (ts in skip range)
__global__ __launch_bounds__(256) void layer_kernel(
    int swap,
    const float* __restrict__ Wd_l, const float* __restrict__ bd_l,
    const float* __restrict__ Ws_l, const float* __restrict__ bs_l,
    const float* __restrict__ Wr_l, const float* __restrict__ br_l,
    int d, int Tout, int skipStart, int first)
{
  const float* xin  = swap ? g_x1 : g_x0;
  float*       xout = swap ? g_x0 : g_x1;
  float*       skip = g_skip;

  __shared__ float xsT[256*33];   // X[k][t], k = 2*c+tap (matches Wd memory order)
  __shared__ float wt[2112];      // weight chunk staging (union of phases)
  __shared__ float actsT[128*33]; // acts[c][t]

  const int tid = threadIdx.x;
  const int b   = blockIdx.y;
  const int t0  = blockIdx.x*32;
  const int nt  = min(32, Tout - t0);

  // ---- Phase A: stage x[t0+t] and x[t0+t+d], transposed
  for (int idx = tid; idx < 32*32; idx += 256){
    int t = idx >> 5, c4 = idx & 31;
    if (t < nt){
      size_t base = ((size_t)(b*T_ + t0 + t))*32 + c4;
      float4 v0 = ((const float4*)xin)[base];
      float4 v1 = ((const float4*)xin)[base + (size_t)d*32];
      int c = c4*4;
      xsT[(2*(c+0)  )*33 + t] = v0.x;
      xsT[(2*(c+1)  )*33 + t] = v0.y;
      xsT[(2*(c+2)  )*33 + t] = v0.z;
      xsT[(2*(c+3)  )*33 + t] = v0.w;
      xsT[(2*(c+0)+1)*33 + t] = v1.x;
      xsT[(2*(c+1)+1)*33 + t] = v1.y;
      xsT[(2*(c+2)+1)*33 + t] = v1.z;
      xsT[(2*(c+3)+1)*33 + t] = v1.w;
    }
  }
  __syncthreads();

  // ---- Phase B: in_act = W[256x256] @ X[256x32]
  const int og = tid & 63;
  const int tg = tid >> 6;
  const int tb = tg*8;
  float a0[8], a1[8], a2[8], a3[8];
  {
    float b0 = bd_l[2*og], b1 = bd_l[2*og+1];
    float b2 = bd_l[128+2*og], b3 = bd_l[128+2*og+1];
#pragma unroll
    for (int j=0;j<8;j++){ a0[j]=b0; a1[j]=b1; a2[j]=b2; a3[j]=b3; }
  }
  for (int kk=0; kk<256; kk+=8){
    { // stage 8 k x 256 o weight chunk: thread = row o, 8 contiguous k
      const float4* wp = (const float4*)(Wd_l + (size_t)tid*256 + kk);
      float4 wa = wp[0], wb = wp[1];
      wt[0*260+tid]=wa.x; wt[1*260+tid]=wa.y; wt[2*260+tid]=wa.z; wt[3*260+tid]=wa.w;
      wt[4*260+tid]=wb.x; wt[5*260+tid]=wb.y; wt[6*260+tid]=wb.z; wt[7*260+tid]=wb.w;
    }
    __syncthreads();
#pragma unroll
    for (int k=0;k<8;k++){
      float xv[8];
#pragma unroll
      for (int j=0;j<8;j++) xv[j] = xsT[(kk+k)*33 + tb + j];
      float2 wA = *(const float2*)&wt[k*260 + 2*og];
      float2 wB = *(const float2*)&wt[k*260 + 128 + 2*og];
#pragma unroll
      for (int j=0;j<8;j++){
        a0[j] = fmaf(wA.x, xv[j], a0[j]);
        a1[j] = fmaf(wA.y, xv[j], a1[j]);
        a2[j] = fmaf(wB.x, xv[j], a2[j]);
        a3[j] = fmaf(wB.y, xv[j], a3[j]);
      }
    }
    __syncthreads();
  }
#pragma unroll
  for (int j=0;j<8;j++){
    actsT[(2*og  )*33 + tb + j] = tanh_(a0[j]) * sigm_(a2[j]);
    actsT[(2*og+1)*33 + tb + j] = tanh_(a1[j]) * sigm_(a3[j]);
  }
  __syncthreads();

  // ---- Phase C: res = Wr[128x128] @ acts + br + x[t+d]
  const int og2 = tid & 31;   // o = og2*4 .. +3
  const int tg2 = tid >> 5;   // t = tg2*4 .. +3
  float rc[4][4];
  {
    float4 brv = *(const float4*)(br_l + og2*4);
#pragma unroll
    for (int tt=0;tt<4;tt++){ rc[0][tt]=brv.x; rc[1][tt]=brv.y; rc[2][tt]=brv.z; rc[3][tt]=brv.w; }
  }
  for (int kk=0;kk<128;kk+=16){
    { // stage 16k x 128o
      int o = tid & 127, half = tid >> 7;
      const float4* wp = (const float4*)(Wr_l + (size_t)o*128 + kk + half*8);
      float4 wa = wp[0], wb = wp[1];
      wt[(half*8+0)*132+o]=wa.x; wt[(half*8+1)*132+o]=wa.y;
      wt[(half*8+2)*132+o]=wa.z; wt[(half*8+3)*132+o]=wa.w;
      wt[(half*8+4)*132+o]=wb.x; wt[(half*8+5)*132+o]=wb.y;
      wt[(half*8+6)*132+o]=wb.z; wt[(half*8+7)*132+o]=wb.w;
    }
    __syncthreads();
#pragma unroll
    for (int k=0;k<16;k++){
      float xv[4];
#pragma unroll
      for (int tt=0;tt<4;tt++) xv[tt] = actsT[(kk+k)*33 + tg2*4 + tt];
      float4 w = *(const float4*)&wt[k*132 + og2*4];
#pragma unroll
      for (int tt=0;tt<4;tt++){
        rc[0][tt]=fmaf(w.x,xv[tt],rc[0][tt]);
        rc[1][tt]=fmaf(w.y,xv[tt],rc[1][tt]);
        rc[2][tt]=fmaf(w.z,xv[tt],rc[2][tt]);
        rc[3][tt]=fmaf(w.w,xv[tt],rc[3][tt]);
      }
    }
    __syncthreads();
  }
#pragma unroll
  for (int tt=0;tt<4;tt++){
    int t = tg2*4+tt;
    if (t < nt){
      int o = og2*4;
      float4 ov;
      ov.x = rc[0][tt] + xsT[(2*(o+0)+1)*33 + t];
      ov.y = rc[1][tt] + xsT[(2*(o+1)+1)*33 + t];
      ov.z = rc[2][tt] + xsT[(2*(o+2)+1)*33 + t];
      ov.w = rc[3][tt] + xsT[(2*(o+3)+1)*33 + t];
      ((float4*)xout)[((size_t)(b*T_ + t0 + t))*32 + og2] = ov;
    }
  }

  // ---- Phase D: skip contribution = Ws[512x128] @ acts + bs
  float sc[8][8];
  {
    float4 ba = *(const float4*)(bs_l + og*8);
    float4 bb = *(const float4*)(bs_l + og*8 + 4);
#pragma unroll
    for (int j=0;j<8;j++){ sc[0][j]=ba.x; sc[1][j]=ba.y; sc[2][j]=ba.z; sc[3][j]=ba.w;
                           sc[4][j]=bb.x; sc[5][j]=bb.y; sc[6][j]=bb.z; sc[7][j]=bb.w; }
  }
  for (int kk=0;kk<128;kk+=4){
    { // stage 4k x 512o
      int o = tid*2;
      float4 wa = *(const float4*)(Ws_l + (size_t)o*128 + kk);
      float4 wb = *(const float4*)(Ws_l + (size_t)(o+1)*128 + kk);
      wt[0*516+o]=wa.x; wt[1*516+o]=wa.y; wt[2*516+o]=wa.z; wt[3*516+o]=wa.w;
      wt[0*516+o+1]=wb.x; wt[1*516+o+1]=wb.y; wt[2*516+o+1]=wb.z; wt[3*516+o+1]=wb.w;
    }
    __syncthreads();
#pragma unroll
    for (int k=0;k<4;k++){
      float xv[8];
#pragma unroll
      for (int j=0;j<8;j++) xv[j] = actsT[(kk+k)*33 + tb + j];
      float4 wlo = *(const float4*)&wt[k*516 + og*8];
      float4 whi = *(const float4*)&wt[k*516 + og*8 + 4];
#pragma unroll
      for (int j=0;j<8;j++){
        sc[0][j]=fmaf(wlo.x,xv[j],sc[0][j]);
        sc[1][j]=fmaf(wlo.y,xv[j],sc[1][j]);
        sc[2][j]=fmaf(wlo.z,xv[j],sc[2][j]);
        sc[3][j]=fmaf(wlo.w,xv[j],sc[3][j]);
        sc[4][j]=fmaf(whi.x,xv[j],sc[4][j]);
        sc[5][j]=fmaf(whi.y,xv[j],sc[5][j]);
        sc[6][j]=fmaf(whi.z,xv[j],sc[6][j]);
        sc[7][j]=fmaf(whi.w,xv[j],sc[7][j]);
      }
    }
    __syncthreads();
  }
#pragma unroll
  for (int j=0;j<8;j++){
    int t = tb + j;
    int ts = t0 + t - skipStart;
    if (t < nt && ts >= 0){
      size_t base = ((size_t)(b*FOUT_) + ts)*512 + og*8;
      float4 lo = make_float4(sc[0][j],sc[1][j],sc[2][j],sc[3][j]);
      float4 hi = make_float4(sc[4][j],sc[5][j],sc[6][j],sc[7][j]);
      if (!first){
        float4 plo = *(const float4*)(skip + base);
        float4 phi = *(const float4*)(skip + base + 4);
        lo.x+=plo.x; lo.y+=plo.y; lo.z+=plo.z; lo.w+=plo.w;
        hi.x+=phi.x; hi.y+=phi.y; hi.z+=phi.z; hi.w+=phi.w;
      }
      *(float4*)(skip + base)     = lo;
      *(float4*)(skip + base + 4) = hi;
    }
  }
}

// ---------------- post1: skip <- relu(W1[512x512] @ relu(skip)), in-place ----------------
// Safe in-place: each block fully reads its own disjoint 32-position tile
// (all kk chunks) before writing it; no inter-block overlap.
__global__ __launch_bounds__(256) void post1_kernel(const float* __restrict__ W1){
  float* skip = g_skip;
  __shared__ float XT[8*33];
  __shared__ float wt[8*516];
  const int tid = threadIdx.x;
  const int b   = blockIdx.y;
  const int t0  = blockIdx.x*32;
  const int nt  = min(32, FOUT_ - t0);
  const int og = tid & 63, tg = tid >> 6;
  const int tb = tg*8;
  float sc[8][8];
#pragma unroll
  for (int i=0;i<8;i++)
#pragma unroll
    for (int j=0;j<8;j++) sc[i][j]=0.f;

  for (int kk=0;kk<512;kk+=8){
    {
      int t = tid >> 3, k = tid & 7;
      float v = 0.f;
      if (t < nt) v = skip[((size_t)(b*FOUT_) + t0 + t)*512 + kk + k];
      XT[k*33 + t] = fmaxf(v, 0.f);
    }
    {
      int o = tid*2;
      const float4* p0 = (const float4*)(W1 + (size_t)o*512 + kk);
      const float4* p1 = (const float4*)(W1 + (size_t)(o+1)*512 + kk);
      float4 a0 = p0[0], a1 = p0[1];
      float4 c0 = p1[0], c1 = p1[1];
      wt[0*516+o]=a0.x; wt[1*516+o]=a0.y; wt[2*516+o]=a0.z; wt[3*516+o]=a0.w;
      wt[4*516+o]=a1.x; wt[5*516+o]=a1.y; wt[6*516+o]=a1.z; wt[7*516+o]=a1.w;
      wt[0*516+o+1]=c0.x; wt[1*516+o+1]=c0.y; wt[2*516+o+1]=c0.z; wt[3*516+o+1]=c0.w;
      wt[4*516+o+1]=c1.x; wt[5*516+o+1]=c1.y; wt[6*516+o+1]=c1.z; wt[7*516+o+1]=c1.w;
    }
    __syncthreads();
#pragma unroll
    for (int k=0;k<8;k++){
      float xv[8];
#pragma unroll
      for (int j=0;j<8;j++) xv[j] = XT[k*33 + tb + j];
      float4 wlo = *(const float4*)&wt[k*516 + og*8];
      float4 whi = *(const float4*)&wt[k*516 + og*8 + 4];
#pragma unroll
      for (int j=0;j<8;j++){
        sc[0][j]=fmaf(wlo.x,xv[j],sc[0][j]);
        sc[1][j]=fmaf(wlo.y,xv[j],sc[1][j]);
        sc[2][j]=fmaf(wlo.z,xv[j],sc[2][j]);
        sc[3][j]=fmaf(wlo.w,xv[j],sc[3][j]);
        sc[4][j]=fmaf(whi.x,xv[j],sc[4][j]);
        sc[5][j]=fmaf(whi.y,xv[j],sc[5][j]);
        sc[6][j]=fmaf(whi.z,xv[j],sc[6][j]);
        sc[7][j]=fmaf(whi.w,xv[j],sc[7][j]);
      }
    }
    __syncthreads();
  }
#pragma unroll
  for (int j=0;j<8;j++){
    int t = tb+j;
    if (t < nt){
      size_t base = ((size_t)(b*FOUT_) + t0 + t)*512 + og*8;
      float4 lo = make_float4(fmaxf(sc[0][j],0.f),fmaxf(sc[1][j],0.f),fmaxf(sc[2][j],0.f),fmaxf(sc[3][j],0.f));
      float4 hi = make_float4(fmaxf(sc[4][j],0.f),fmaxf(sc[5][j],0.f),fmaxf(sc[6][j],0.f),fmaxf(sc[7][j],0.f));
      *(float4*)(skip + base)     = lo;
      *(float4*)(skip + base + 4) = hi;
    }
  }
}

// ---------------- post2: out[b][o][t] = W2[256x512] @ h1 ----------------
__global__ __launch_bounds__(256) void post2_kernel(const float* __restrict__ W2,
                                                    float* __restrict__ out){
  const float* h1 = g_skip;
  __shared__ float XT[8*33];
  __shared__ float wt[8*260];
  const int tid = threadIdx.x;
  const int b   = blockIdx.y;
  const int t0  = blockIdx.x*32;
  const int nt  = min(32, FOUT_ - t0);
  const int og = tid & 63, tg = tid >> 6;
  const int tb = tg*8;
  float ac[4][8];
#pragma unroll
  for (int i=0;i<4;i++)
#pragma unroll
    for (int j=0;j<8;j++) ac[i][j]=0.f;

  for (int kk=0;kk<512;kk+=8){
    {
      int t = tid >> 3, k = tid & 7;
      float v = 0.f;
      if (t < nt) v = h1[((size_t)(b*FOUT_) + t0 + t)*512 + kk + k];
      XT[k*33 + t] = v;
    }
    {
      int o = tid;
      const float4* p = (const float4*)(W2 + (size_t)o*512 + kk);
      float4 a0 = p[0], a1 = p[1];
      wt[0*260+o]=a0.x; wt[1*260+o]=a0.y; wt[2*260+o]=a0.z; wt[3*260+o]=a0.w;
      wt[4*260+o]=a1.x; wt[5*260+o]=a1.y; wt[6*260+o]=a1.z; wt[7*260+o]=a1.w;
    }
    __syncthreads();
#pragma unroll
    for (int k=0;k<8;k++){
      float xv[8];
#pragma unroll
      for (int j=0;j<8;j++) xv[j] = XT[k*33 + tb + j];
      float4 w = *(const float4*)&wt[k*260 + og*4];
#pragma unroll
      for (int j=0;j<8;j++){
        ac[0][j]=fmaf(w.x,xv[j],ac[0][j]);
        ac[1][j]=fmaf(w.y,xv[j],ac[1][j]);
        ac[2][j]=fmaf(w.z,xv[j],ac[2][j]);
        ac[3][j]=fmaf(w.w,xv[j],ac[3][j]);
      }
    }
    __syncthreads();
  }
#pragma unroll
  for (int j=0;j<8;j++){
    int t = tb+j;
    if (t < nt){
#pragma unroll
      for (int i=0;i<4;i++){
        out[((size_t)(b*256) + og*4 + i)*FOUT_ + t0 + t] = ac[i][j];
      }
    }
  }
}

// ---------------- host launch ----------------
extern "C" void kernel_launch(void* const* d_in, const int* in_sizes, int n_in,
                              void* d_out, int out_size, void* d_ws, size_t ws_size,
                              hipStream_t stream) {
  const int*   y     = (const int*)  d_in[0];
  const float* embed = (const float*)d_in[1];
  const float* Wd    = (const float*)d_in[2];
  const float* bd    = (const float*)d_in[3];
  const float* Ws    = (const float*)d_in[4];
  const float* bs    = (const float*)d_in[5];
  const float* Wr    = (const float*)d_in[6];
  const float* br    = (const float*)d_in[7];
  const float* W1    = (const float*)d_in[8];
  const float* W2    = (const float*)d_in[9];
  float* out = (float*)d_out;
  (void)d_ws; (void)ws_size;

  embed_kernel<<<dim3((B_*T_*32)/256), dim3(256), 0, stream>>>(y, embed);

  static const int DIL[NL_] = {1,2,4,8,16,32,64,128,256,512,
                               1,2,4,8,16,32,64,128,256,512};
  int swap = 0;  // 0: read x0 write x1, 1: read x1 write x0
  int Tin = T_;
  for (int i=0;i<NL_;i++){
    int d = DIL[i];
    int Tout = Tin - d;
    dim3 grid((Tout+31)/32, B_);
    layer_kernel<<<grid, dim3(256), 0, stream>>>(
        swap,
        Wd + (size_t)i*2*WD_*WD_*2, bd + (size_t)i*2*WD_,
        Ws + (size_t)i*SD_*WD_,     bs + (size_t)i*SD_,
        Wr + (size_t)i*WD_*WD_,     br + (size_t)i*WD_,
        d, Tout, Tout - FOUT_, (i==0)?1:0);
    swap ^= 1;
    Tin = Tout;
  }

  dim3 pg((FOUT_+31)/32, B_);
  post1_kernel<<<pg, dim3(256), 0, stream>>>(W1);
  post2_kernel<<<pg, dim3(256), 0, stream>>>(W2, out);
}

// Round 3
// 1370.979 us; speedup vs baseline: 5.6439x; 5.6439x over previous
//
#include <hip/hip_runtime.h>
#include <cstddef>

#define B_    4
#define T_    16384
#define WD_   128
#define SD_   512
#define FOUT_ 14337
#define NL_   20
#define NTOT_ (B_*FOUT_)              // 57348
#define ACTS_LSTRIDE ((size_t)B_*FOUT_*WD_)

typedef float f32x4 __attribute__((ext_vector_type(4)));
typedef short bf16x8 __attribute__((ext_vector_type(8)));

// ---- static device buffers (rewritten every call; no ws_size dependence) ----
__device__ float g_x0[(size_t)B_*T_*WD_];
__device__ float g_x1[(size_t)B_*T_*WD_];
__device__ unsigned short g_WdB[(size_t)NL_*256*256];
__device__ unsigned short g_WrB[(size_t)NL_*128*128];
__device__ unsigned short g_WsBig[(size_t)512*2560];
__device__ unsigned short g_W1B[(size_t)512*512];
__device__ unsigned short g_W2B[(size_t)256*512];
__device__ float g_bssum[512];
__device__ unsigned short g_acts[(size_t)NL_*ACTS_LSTRIDE];   // bf16 [l][b*FOUT+ts][128]
__device__ unsigned short g_skipB[(size_t)NTOT_*512];         // bf16 relu(skip) [n][512]
__device__ unsigned short g_h1B[(size_t)NTOT_*512];           // bf16 relu(h1)   [n][512]

__device__ __forceinline__ unsigned short f2bf(float f){
  unsigned u = __float_as_uint(f);
  u += 0x7FFF + ((u >> 16) & 1u);
  return (unsigned short)(u >> 16);
}
__device__ __forceinline__ float sigm_(float x){ return 1.0f/(1.0f+__expf(-x)); }
__device__ __forceinline__ float tanh_(float x){ return 1.0f - 2.0f/(__expf(2.0f*x)+1.0f); }
__device__ __forceinline__ f32x4 MFMA(bf16x8 a, bf16x8 b, f32x4 c){
  return __builtin_amdgcn_mfma_f32_16x16x32_bf16(a, b, c, 0, 0, 0);
}

// ---------------- weight conversion ----------------
__global__ void cvt_flat(const float* __restrict__ src, int which, int n4){
  int i = blockIdx.x*256 + threadIdx.x;
  if (i >= n4) return;
  unsigned short* dst = (which==0)?g_WdB:(which==1)?g_WrB:(which==2)?g_W1B:g_W2B;
  float4 v = ((const float4*)src)[i];
  ushort4 o; o.x=f2bf(v.x); o.y=f2bf(v.y); o.z=f2bf(v.z); o.w=f2bf(v.w);
  ((ushort4*)dst)[i] = o;
}
// Ws [L][512][128] -> Wbig bf16 [512][2560], col = l*128+k
__global__ void cvt_ws(const float* __restrict__ Ws){
  int gid = blockIdx.x*256 + threadIdx.x;          // n4 = 20*512*32 = 327680
  if (gid >= NL_*512*32) return;
  int l = gid >> 14; int rem = gid & 16383;
  int o = rem >> 5;  int k4 = rem & 31;
  float4 v = ((const float4*)Ws)[((size_t)(l*512+o))*32 + k4];
  ushort4 t; t.x=f2bf(v.x); t.y=f2bf(v.y); t.z=f2bf(v.z); t.w=f2bf(v.w);
  ((ushort4*)g_WsBig)[(size_t)o*640 + l*32 + k4] = t;
}
__global__ void bssum_k(const float* __restrict__ bs){
  int o = threadIdx.x;
  float s = 0.f;
  for (int l=0;l<NL_;l++) s += bs[l*512 + o];
  g_bssum[o] = s;
}

// ---------------- embedding ----------------
__global__ void embed_kernel(const int* __restrict__ y, const float* __restrict__ embed){
  int gid = blockIdx.x*256 + threadIdx.x;
  int bt  = gid >> 5;
  int c4  = gid & 31;
  if (bt < B_*T_){
    int idx = y[bt];
    float4 v = ((const float4*)embed)[(size_t)idx*32 + c4];
    ((float4*)g_x0)[(size_t)bt*32 + c4] = v;
  }
}

// ---------------- fused layer: in_act MFMA -> gate -> acts (LDS + global bf16) -> res MFMA ----------------
// 64 time positions per block, 256 threads (4 waves).
__global__ __launch_bounds__(256) void layer_mfma(
    int swap, int l, int d, int Tout, int skipStart,
    const float* __restrict__ bd_l, const float* __restrict__ br_l)
{
  const float* __restrict__ xin  = swap ? g_x1 : g_x0;
  float* __restrict__       xout = swap ? g_x0 : g_x1;
  const unsigned short* __restrict__ WdB = g_WdB + (size_t)l*65536;
  const unsigned short* __restrict__ WrB = g_WrB + (size_t)l*16384;
  unsigned short* __restrict__ actsG = g_acts + (size_t)l*ACTS_LSTRIDE;

  __shared__ unsigned short Xb[64*264];     // [t][k=2c+tap], pad 256->264
  __shared__ unsigned short actsB[64*136];  // [t][c], pad 128->136

  const int tid = threadIdx.x;
  const int w   = tid >> 6;
  const int lane= tid & 63;
  const int q   = lane >> 4;
  const int ln  = lane & 15;
  const int b   = blockIdx.y;
  const int t0g = blockIdx.x*64;
  const int ntv = min(64, Tout - t0g);

  // Phase A: stage x taps -> bf16 interleaved [t][2c+tap]
  const float4* x4 = (const float4*)xin;
  for (int idx = tid; idx < 64*32; idx += 256){
    int t = idx >> 5, c4 = idx & 31;
    int tc = (t < ntv) ? t : (ntv-1);
    size_t base = ((size_t)b*T_ + t0g + tc)*32 + c4;
    float4 v0 = x4[base];
    float4 v1 = x4[base + (size_t)d*32];
    union { unsigned short u[8]; uint4 v; } pk;
    pk.u[0]=f2bf(v0.x); pk.u[1]=f2bf(v1.x);
    pk.u[2]=f2bf(v0.y); pk.u[3]=f2bf(v1.y);
    pk.u[4]=f2bf(v0.z); pk.u[5]=f2bf(v1.z);
    pk.u[6]=f2bf(v0.w); pk.u[7]=f2bf(v1.w);
    *(uint4*)((void*)&Xb[t*264 + c4*8]) = pk.v;
  }
  __syncthreads();

  // Phase B: in_act[256][64]; wave w owns tanh rows w*32..+31 and sigm rows 128+w*32..+31
  f32x4 accB[4][4];
  for (int mi=0;mi<4;mi++){
    int mrow = (mi<2) ? (w*32 + mi*16) : (128 + w*32 + (mi-2)*16);
    float4 bv = *(const float4*)(bd_l + mrow + q*4);
    f32x4 bi; bi[0]=bv.x; bi[1]=bv.y; bi[2]=bv.z; bi[3]=bv.w;
    for (int nt=0;nt<4;nt++) accB[mi][nt] = bi;
  }
  for (int ks=0; ks<8; ks++){
    bf16x8 bfr[4];
#pragma unroll
    for (int nt=0;nt<4;nt++)
      bfr[nt] = *(const bf16x8*)((const void*)&Xb[(nt*16+ln)*264 + ks*32 + q*8]);
    bf16x8 afr[4];
#pragma unroll
    for (int mi=0;mi<4;mi++){
      int row = ((mi<2) ? (w*32 + mi*16) : (128 + w*32 + (mi-2)*16)) + ln;
      afr[mi] = *(const bf16x8*)((const void*)(WdB + (size_t)row*256 + ks*32 + q*8));
    }
#pragma unroll
    for (int mi=0;mi<4;mi++)
#pragma unroll
      for (int nt=0;nt<4;nt++)
        accB[mi][nt] = MFMA(afr[mi], bfr[nt], accB[mi][nt]);
  }

  // gate -> acts (bf16): LDS + global
#pragma unroll
  for (int mi=0;mi<2;mi++)
#pragma unroll
    for (int nt=0;nt<4;nt++){
      f32x4 vt = accB[mi][nt], vs = accB[mi+2][nt];
      ushort4 pk;
      pk.x = f2bf(tanh_(vt[0])*sigm_(vs[0]));
      pk.y = f2bf(tanh_(vt[1])*sigm_(vs[1]));
      pk.z = f2bf(tanh_(vt[2])*sigm_(vs[2]));
      pk.w = f2bf(tanh_(vt[3])*sigm_(vs[3]));
      int tl = nt*16 + ln;
      int c0 = w*32 + mi*16 + q*4;
      *(ushort4*)((void*)&actsB[tl*136 + c0]) = pk;
      int ts = t0g + tl - skipStart;
      if (tl < ntv && ts >= 0)
        *(ushort4*)((void*)(actsG + ((size_t)b*FOUT_ + ts)*128 + c0)) = pk;
    }
  __syncthreads();

  // Phase C: res[128][64] = Wr@acts + br + x[t+d]
  f32x4 accC[2][4];
  for (int mi=0;mi<2;mi++){
    float4 bv = *(const float4*)(br_l + w*32 + mi*16 + q*4);
    f32x4 bi; bi[0]=bv.x; bi[1]=bv.y; bi[2]=bv.z; bi[3]=bv.w;
    for (int nt=0;nt<4;nt++) accC[mi][nt] = bi;
  }
  for (int ks=0; ks<4; ks++){
    bf16x8 bfr[4];
#pragma unroll
    for (int nt=0;nt<4;nt++)
      bfr[nt] = *(const bf16x8*)((const void*)&actsB[(nt*16+ln)*136 + ks*32 + q*8]);
    bf16x8 afr[2];
#pragma unroll
    for (int mi=0;mi<2;mi++){
      int row = w*32 + mi*16 + ln;
      afr[mi] = *(const bf16x8*)((const void*)(WrB + (size_t)row*128 + ks*32 + q*8));
    }
#pragma unroll
    for (int mi=0;mi<2;mi++)
#pragma unroll
      for (int nt=0;nt<4;nt++)
        accC[mi][nt] = MFMA(afr[mi], bfr[nt], accC[mi][nt]);
  }
#pragma unroll
  for (int mi=0;mi<2;mi++)
#pragma unroll
    for (int nt=0;nt<4;nt++){
      int tl = nt*16 + ln;
      if (tl < ntv){
        int c4i = w*8 + mi*4 + q;   // (c0)/4
        float4 xr = x4[((size_t)b*T_ + t0g + tl + d)*32 + c4i];
        f32x4 v = accC[mi][nt];
        float4 ov; ov.x = v[0]+xr.x; ov.y = v[1]+xr.y; ov.z = v[2]+xr.z; ov.w = v[3]+xr.w;
        ((float4*)xout)[((size_t)b*T_ + t0g + tl)*32 + c4i] = ov;
      }
    }
}

// ---------------- big GEMM template: C[M][N] = A@X (+bias)(relu) ----------------
// MODE 0: skip = Wbig[512x2560] @ acts + bs_sum, relu -> bf16 g_skipB
// MODE 1: h1   = W1  [512x512]  @ skipB, relu -> bf16 g_h1B
// MODE 2: out  = W2  [256x512]  @ h1B -> fp32 out[b][o][t]
// block: 512 threads (8 waves), tile M=256 x N=128, K-chunk 64.
template<int MODE>
__global__ __launch_bounds__(512) void gemm_big(float* __restrict__ outF){
  constexpr int KTOT  = (MODE==0)?2560:512;
  constexpr int KCLOG = (MODE==0)?7:9;
  constexpr bool RELU = (MODE!=2);
  constexpr int MROWS = (MODE==2)?256:512;
  const unsigned short* __restrict__ A = (MODE==0)?g_WsBig:(MODE==1)?g_W1B:g_W2B;
  const unsigned short* __restrict__ X = (MODE==0)?g_acts:(MODE==1)?g_skipB:g_h1B;
  unsigned short* __restrict__ outB = (MODE==0)?g_skipB:g_h1B;
  const float* bias = (MODE==0)?g_bssum:nullptr;
  const size_t lstr = (MODE==0)?ACTS_LSTRIDE:(size_t)0;

  __shared__ unsigned short Xs[128*72];   // [n][k-chunk 64], pad->72

  const int tid = threadIdx.x;
  const int w   = tid >> 6;
  const int lane= tid & 63;
  const int q   = lane >> 4;
  const int ln  = lane & 15;
  const int n0  = blockIdx.x*128;
  const int m0  = blockIdx.y*256;

  f32x4 acc[2][8];
  for (int mi=0;mi<2;mi++)
    for (int nt=0;nt<8;nt++){ f32x4 z; z[0]=0;z[1]=0;z[2]=0;z[3]=0; acc[mi][nt]=z; }

  for (int kc0=0; kc0<KTOT; kc0+=64){
#pragma unroll
    for (int r=0;r<2;r++){
      int idx = tid + r*512;
      int nn = idx >> 3, kk = (idx & 7)*8;
      int ng = n0 + nn; if (ng >= NTOT_) ng = NTOT_-1;
      int kb = kc0 + kk;
      int li = kb >> KCLOG;
      int ko = kb & ((1<<KCLOG)-1);
      const unsigned short* src = X + (size_t)li*lstr + (size_t)ng*(1<<KCLOG) + ko;
      *(uint4*)((void*)&Xs[nn*72 + kk]) = *(const uint4*)((const void*)src);
    }
    __syncthreads();
    bf16x8 afr[2][2];
#pragma unroll
    for (int kst=0;kst<2;kst++)
#pragma unroll
      for (int mi=0;mi<2;mi++){
        int row = m0 + w*32 + mi*16 + ln;
        afr[kst][mi] = *(const bf16x8*)((const void*)(A + (size_t)row*KTOT + kc0 + kst*32 + q*8));
      }
#pragma unroll
    for (int kst=0;kst<2;kst++){
      bf16x8 bfr[8];
#pragma unroll
      for (int nt=0;nt<8;nt++)
        bfr[nt] = *(const bf16x8*)((const void*)&Xs[(nt*16+ln)*72 + kst*32 + q*8]);
#pragma unroll
      for (int mi=0;mi<2;mi++)
#pragma unroll
        for (int nt=0;nt<8;nt++)
          acc[mi][nt] = MFMA(afr[kst][mi], bfr[nt], acc[mi][nt]);
    }
    __syncthreads();
  }

#pragma unroll
  for (int mi=0;mi<2;mi++)
#pragma unroll
    for (int nt=0;nt<8;nt++){
      int m  = m0 + w*32 + mi*16 + q*4;
      int ng = n0 + nt*16 + ln;
      if (ng < NTOT_){
        f32x4 v = acc[mi][nt];
        if (MODE==0){
          float4 bv = *(const float4*)(bias + m);
          v[0]+=bv.x; v[1]+=bv.y; v[2]+=bv.z; v[3]+=bv.w;
        }
        if (RELU){
          v[0]=fmaxf(v[0],0.f); v[1]=fmaxf(v[1],0.f);
          v[2]=fmaxf(v[2],0.f); v[3]=fmaxf(v[3],0.f);
        }
        if (MODE!=2){
          ushort4 pk; pk.x=f2bf(v[0]); pk.y=f2bf(v[1]); pk.z=f2bf(v[2]); pk.w=f2bf(v[3]);
          *(ushort4*)((void*)(outB + (size_t)ng*MROWS + m)) = pk;
        } else {
          int bb = ng / FOUT_;
          int ts = ng - bb*FOUT_;
#pragma unroll
          for (int r2=0;r2<4;r2++)
            outF[((size_t)bb*256 + m + r2)*FOUT_ + ts] = v[r2];
        }
      }
    }
}

// ---------------- host launch ----------------
extern "C" void kernel_launch(void* const* d_in, const int* in_sizes, int n_in,
                              void* d_out, int out_size, void* d_ws, size_t ws_size,
                              hipStream_t stream) {
  const int*   y     = (const int*)  d_in[0];
  const float* embed = (const float*)d_in[1];
  const float* Wd    = (const float*)d_in[2];
  const float* bd    = (const float*)d_in[3];
  const float* Ws    = (const float*)d_in[4];
  const float* bs    = (const float*)d_in[5];
  const float* Wr    = (const float*)d_in[6];
  const float* br    = (const float*)d_in[7];
  const float* W1    = (const float*)d_in[8];
  const float* W2    = (const float*)d_in[9];
  float* out = (float*)d_out;
  (void)d_ws; (void)ws_size;

  // weight conversion (weights are re-poisoned before every timed launch)
  cvt_flat<<<dim3((327680+255)/256), dim3(256), 0, stream>>>(Wd, 0, 327680);
  cvt_flat<<<dim3(( 81920+255)/256), dim3(256), 0, stream>>>(Wr, 1,  81920);
  cvt_flat<<<dim3(( 65536+255)/256), dim3(256), 0, stream>>>(W1, 2,  65536);
  cvt_flat<<<dim3(( 32768+255)/256), dim3(256), 0, stream>>>(W2, 3,  32768);
  cvt_ws  <<<dim3((327680+255)/256), dim3(256), 0, stream>>>(Ws);
  bssum_k <<<dim3(1), dim3(512), 0, stream>>>(bs);

  embed_kernel<<<dim3((B_*T_*32)/256), dim3(256), 0, stream>>>(y, embed);

  static const int DIL[NL_] = {1,2,4,8,16,32,64,128,256,512,
                               1,2,4,8,16,32,64,128,256,512};
  int swap = 0;
  int Tin = T_;
  for (int i=0;i<NL_;i++){
    int d = DIL[i];
    int Tout = Tin - d;
    dim3 grid((Tout+63)/64, B_);
    layer_mfma<<<grid, dim3(256), 0, stream>>>(
        swap, i, d, Tout, Tout - FOUT_, bd + (size_t)i*256, br + (size_t)i*128);
    swap ^= 1;
    Tin = Tout;
  }

  dim3 g2((NTOT_+127)/128, 2);
  dim3 g1((NTOT_+127)/128, 1);
  gemm_big<0><<<g2, dim3(512), 0, stream>>>(nullptr);
  gemm_big<1><<<g2, dim3(512), 0, stream>>>(nullptr);
  gemm_big<2><<<g1, dim3(512), 0, stream>>>(out);
}